// Round 3
// baseline (2333.026 us; speedup 1.0000x reference)
//
#include <hip/hip_runtime.h>

typedef unsigned short ushort_t;
typedef __attribute__((ext_vector_type(8))) short short8;
typedef __attribute__((ext_vector_type(4))) float floatx4;

#define MFMA16x16x32(a, b, c) __builtin_amdgcn_mfma_f32_16x16x32_bf16(a, b, c, 0, 0, 0)

__device__ __forceinline__ float bf2f(ushort_t h) {
    unsigned int u = ((unsigned int)h) << 16;
    return __builtin_bit_cast(float, u);
}
__device__ __forceinline__ ushort_t f2bf(float f) {
    unsigned int u = __builtin_bit_cast(unsigned int, f);
    u += 0x7fffu + ((u >> 16) & 1u);
    return (ushort_t)(u >> 16);
}
__device__ __forceinline__ void gload_lds16(const ushort_t* g, ushort_t* l) {
    __builtin_amdgcn_global_load_lds(
        (const __attribute__((address_space(1))) unsigned int*)g,
        (__attribute__((address_space(3))) unsigned int*)l, 16, 0, 0);
}

// ---------------------------------------------------------------------------
// fp32 -> bf16 (RNE) conversion, 8 elems/thread, grid-stride.
// ---------------------------------------------------------------------------
__global__ __launch_bounds__(256) void conv_bf16(const float* __restrict__ in,
                                                 ushort_t* __restrict__ out, int n8) {
    int i = blockIdx.x * 256 + threadIdx.x;
    const int stride = gridDim.x * 256;
    for (; i < n8; i += stride) {
        const float* p = in + (size_t)i * 8;
        floatx4 a0 = *(const floatx4*)p;
        floatx4 a1 = *(const floatx4*)(p + 4);
        short8 o;
        o[0] = (short)f2bf(a0[0]); o[1] = (short)f2bf(a0[1]);
        o[2] = (short)f2bf(a0[2]); o[3] = (short)f2bf(a0[3]);
        o[4] = (short)f2bf(a1[0]); o[5] = (short)f2bf(a1[1]);
        o[6] = (short)f2bf(a1[2]); o[7] = (short)f2bf(a1[3]);
        *(short8*)(out + (size_t)i * 8) = o;
    }
}

// ---------------------------------------------------------------------------
// LayerNorm: one block per row of 2048. INF32=1: fp32 input (original x),
// INF32=0: bf16 input (x2 residual buffer). Params bf16, output bf16.
// ---------------------------------------------------------------------------
template <int INF32>
__global__ __launch_bounds__(256) void ln_kernel(const void* __restrict__ in,
                                                 const ushort_t* __restrict__ w,
                                                 const ushort_t* __restrict__ b,
                                                 ushort_t* __restrict__ out) {
    const int row = blockIdx.x;
    const int tid = threadIdx.x;
    const size_t base = (size_t)row * 2048 + (size_t)tid * 8;
    float v[8];
    if (INF32) {
        const float* p = (const float*)in + base;
        floatx4 a0 = *(const floatx4*)p;
        floatx4 a1 = *(const floatx4*)(p + 4);
        v[0] = a0[0]; v[1] = a0[1]; v[2] = a0[2]; v[3] = a0[3];
        v[4] = a1[0]; v[5] = a1[1]; v[6] = a1[2]; v[7] = a1[3];
    } else {
        short8 hv = *(const short8*)((const ushort_t*)in + base);
        const ushort_t* hp = (const ushort_t*)&hv;
#pragma unroll
        for (int k = 0; k < 8; k++) v[k] = bf2f(hp[k]);
    }
    float s = 0.f, sq = 0.f;
#pragma unroll
    for (int k = 0; k < 8; k++) { s += v[k]; sq += v[k] * v[k]; }
#pragma unroll
    for (int m = 32; m; m >>= 1) { s += __shfl_xor(s, m); sq += __shfl_xor(sq, m); }
    __shared__ float red[8];
    const int wv = tid >> 6;
    if ((tid & 63) == 0) { red[wv] = s; red[4 + wv] = sq; }
    __syncthreads();
    s = red[0] + red[1] + red[2] + red[3];
    sq = red[4] + red[5] + red[6] + red[7];
    const float mu = s * (1.f / 2048.f);
    const float var = fmaxf(sq * (1.f / 2048.f) - mu * mu, 0.f);
    const float rs = rsqrtf(var + 1e-5f);
    short8 ov;
#pragma unroll
    for (int k = 0; k < 8; k++) {
        const int c = tid * 8 + k;
        float y = (v[k] - mu) * rs * bf2f(w[c]) + bf2f(b[c]);
        ov[k] = (short)f2bf(y);
    }
    *(short8*)(out + base) = ov;
}

// ---------------------------------------------------------------------------
// GEMM: C[M,N] = A[M,K] * W[N,K]^T + bias (A,W,bias bf16), fused epilogues.
// m97 structure: 128x128 tile, BK=32, 256 thr (4 waves, 2x2 of 64x64),
// global_load_lds width-16 staging, 16x16x32 bf16 MFMA.
// EPI 0: +bias, pre-scale Q cols (n<2048) by 1/sqrt(128) -> bf16   (QKV)
// EPI 1: +bias +fp32 residual -> bf16 out         (attn out-proj -> x2)
// EPI 2: +bias, exact GELU -> bf16 out            (MLP up)
// EPI 3: +bias +bf16 residual -> FP32 out         (MLP down -> final output)
// ---------------------------------------------------------------------------
template <int EPI>
__global__ __launch_bounds__(256) void gemm_bt(const ushort_t* __restrict__ A,
                                               const ushort_t* __restrict__ W,
                                               const ushort_t* __restrict__ bias,
                                               const void* __restrict__ res,
                                               void* __restrict__ out,
                                               int M, int N, int K) {
    __shared__ ushort_t As[4096];  // [128][32]
    __shared__ ushort_t Bs[4096];  // [128][32]
    const int tid = threadIdx.x;
    const int lane = tid & 63;
    const int wave = tid >> 6;
    const int nbn = N >> 7;
    const int bm = blockIdx.x / nbn;
    const int bn = blockIdx.x % nbn;
    const int wm = (wave >> 1) * 64;
    const int wn = (wave & 1) * 64;
    const int la = lane & 15;
    const int qd = lane >> 4;

    floatx4 acc[4][4];
    const floatx4 z4 = {0.f, 0.f, 0.f, 0.f};
#pragma unroll
    for (int i = 0; i < 4; i++)
#pragma unroll
        for (int j = 0; j < 4; j++) acc[i][j] = z4;

    const ushort_t* ga = A + (size_t)(bm * 128 + (tid >> 2)) * K + (tid & 3) * 8;
    const ushort_t* gb = W + (size_t)(bn * 128 + (tid >> 2)) * K + (tid & 3) * 8;
    ushort_t* lA = As + (size_t)(tid & ~63) * 8;
    ushort_t* lB = Bs + (size_t)(tid & ~63) * 8;
    const size_t strideR = (size_t)64 * K;

    for (int kt = 0; kt < K; kt += 32) {
        __syncthreads();
        gload_lds16(ga + kt, lA);
        gload_lds16(ga + kt + strideR, lA + 2048);
        gload_lds16(gb + kt, lB);
        gload_lds16(gb + kt + strideR, lB + 2048);
        __syncthreads();
        short8 af[4], bfr[4];
#pragma unroll
        for (int i = 0; i < 4; i++) af[i] = *(const short8*)&As[(wm + i * 16 + la) * 32 + qd * 8];
#pragma unroll
        for (int j = 0; j < 4; j++) bfr[j] = *(const short8*)&Bs[(wn + j * 16 + la) * 32 + qd * 8];
#pragma unroll
        for (int i = 0; i < 4; i++)
#pragma unroll
            for (int j = 0; j < 4; j++) acc[i][j] = MFMA16x16x32(af[i], bfr[j], acc[i][j]);
    }

#pragma unroll
    for (int i = 0; i < 4; i++) {
#pragma unroll
        for (int j = 0; j < 4; j++) {
#pragma unroll
            for (int r = 0; r < 4; r++) {
                const int m = bm * 128 + wm + i * 16 + qd * 4 + r;
                const int n = bn * 128 + wn + j * 16 + la;
                const size_t idx = (size_t)m * N + n;
                float v = acc[i][j][r] + bf2f(bias[n]);
                if (EPI == 0) {
                    if (n < 2048) v *= 0.08838834764831845f;  // pre-scale Q
                    ((ushort_t*)out)[idx] = f2bf(v);
                } else if (EPI == 1) {
                    v += ((const float*)res)[idx];
                    ((ushort_t*)out)[idx] = f2bf(v);
                } else if (EPI == 2) {
                    v = 0.5f * v * (1.f + erff(v * 0.70710678118654752f));
                    ((ushort_t*)out)[idx] = f2bf(v);
                } else {
                    v += bf2f(((const ushort_t*)res)[idx]);
                    ((float*)out)[idx] = v;
                }
            }
        }
    }
}

// ---------------------------------------------------------------------------
// Flash attention with ALiBi + causal. One WG (256 thr) per (b, h, 64-row
// q-tile). 64-col K/V tiles. Each wave owns 16 q-rows. QK^T and PV via
// 16x16x32 bf16 MFMA.
//   - Q pre-scaled by 1/sqrt(128) in the QKV GEMM epilogue.
//   - ALiBi row term -slope*q is softmax-invariant -> dropped; only the
//     column term slope*k is added. Causal mask only on the diagonal tile.
//   - LDS 40960 B exactly (Q staging aliased onto Ks) -> 4 WG/CU.
//   - P-store XOR-swizzled (2-way max); V transposed with chunk swizzle.
// qkv layout: [B*S, 6144] rows = [q|k|v] bf16.
// ---------------------------------------------------------------------------
__global__ __launch_bounds__(256, 4) void attn_kernel(const ushort_t* __restrict__ qkv,
                                                      const float* __restrict__ slopes,
                                                      ushort_t* __restrict__ out) {
    __shared__ ushort_t smem[20480];     // 40960 B total
    ushort_t* Ks = smem;                 // [64][128], aliased with Q staging
    ushort_t* Vt = smem + 8192;          // [128][64] chunk-swizzled
    ushort_t* Ps = smem + 16384;         // 4 waves x [16][64] XOR-swizzled
    const int tid = threadIdx.x;
    const int lane = tid & 63;
    const int wave = tid >> 6;
    const int la = lane & 15;
    const int qd = lane >> 4;
    const int qt = blockIdx.x;
    const int h = blockIdx.y;
    const int b = blockIdx.z;
    const float slope = slopes[h];
    const size_t RS = 6144;

    const ushort_t* Qb = qkv + (size_t)b * 2048 * RS + h * 128;
    const ushort_t* Kb = Qb + 2048;
    const ushort_t* Vb = Qb + 4096;

    // Stage Q tile [64][128] into Ks region; LDS slot (row, cs) holds global
    // chunk cs^(row&15).
#pragma unroll
    for (int p = 0; p < 4; p++) {
        const int f = p * 256 + tid;
        const int r = f >> 4;
        const int cs = f & 15;
        gload_lds16(Qb + (size_t)(qt * 64 + r) * RS + (size_t)(cs ^ (r & 15)) * 8,
                    Ks + (size_t)(p * 256 + (tid & ~63)) * 8);
    }
    __syncthreads();
    short8 qa[4];
#pragma unroll
    for (int ks = 0; ks < 4; ks++)
        qa[ks] = *(const short8*)&Ks[(wave * 16 + la) * 128 + ((ks * 4 + qd) ^ la) * 8];
    // Loop-top barrier protects Ks overwrite after all waves read qa.

    floatx4 accO[8];
    const floatx4 z4 = {0.f, 0.f, 0.f, 0.f};
#pragma unroll
    for (int dt = 0; dt < 8; dt++) accO[dt] = z4;
    float mst[4] = {-1e30f, -1e30f, -1e30f, -1e30f};
    float lst[4] = {0.f, 0.f, 0.f, 0.f};

    for (int kt = 0; kt <= qt; kt++) {
        __syncthreads();  // prev iter finished reading Ks/Vt (and qa reads)
#pragma unroll
        for (int p = 0; p < 4; p++) {
            const int f = p * 256 + tid;
            const int r = f >> 4;
            const int cs = f & 15;
            gload_lds16(Kb + (size_t)(kt * 64 + r) * RS + (size_t)(cs ^ (r & 15)) * 8,
                        Ks + (size_t)(p * 256 + (tid & ~63)) * 8);
        }
        // V transposed: Vt[d][k], k-chunks XOR-swizzled by (d&7); write order
        // rotated by lane to spread banks.
#pragma unroll
        for (int p = 0; p < 4; p++) {
            const int f = p * 256 + tid;
            const int r = f >> 4;          // k index 0..63
            const int c8 = (f & 15) * 8;   // d base
            short8 vv = *(const short8*)(Vb + (size_t)(kt * 64 + r) * RS + c8);
            const ushort_t* vs = (const ushort_t*)&vv;
            const int chunk = r >> 3;
            const int koff = r & 7;
#pragma unroll
            for (int s = 0; s < 8; s++) {
                const int i = (s + lane) & 7;
                const int d = c8 + i;
                Vt[d * 64 + (chunk ^ i) * 8 + koff] = vs[i];
            }
        }
        __syncthreads();

        // S = (Q/sqrt(d)) K^T  (per wave: 16 rows x 64 cols)
        floatx4 sc[4];
#pragma unroll
        for (int nt = 0; nt < 4; nt++) sc[nt] = z4;
#pragma unroll
        for (int nt = 0; nt < 4; nt++) {
#pragma unroll
            for (int ks = 0; ks < 4; ks++) {
                short8 kb = *(const short8*)&Ks[(nt * 16 + la) * 128 + ((ks * 4 + qd) ^ la) * 8];
                sc[nt] = MFMA16x16x32(qa[ks], kb, sc[nt]);
            }
        }

        // Online softmax (row shift-invariant: only column ALiBi term).
        const int knb = kt * 64;
        const bool diag = (kt == qt);
        float acol[4];
#pragma unroll
        for (int nt = 0; nt < 4; nt++) acol[nt] = slope * (float)(knb + nt * 16 + la);
        float pb[4][4];
#pragma unroll
        for (int r = 0; r < 4; r++) {
            float rmax = -1e30f;
#pragma unroll
            for (int nt = 0; nt < 4; nt++) {
                float sval = sc[nt][r] + acol[nt];
                if (diag) {
                    const int qloc = wave * 16 + qd * 4 + r;
                    if (nt * 16 + la > qloc) sval = -1e30f;
                }
                pb[nt][r] = sval;
                rmax = fmaxf(rmax, sval);
            }
            rmax = fmaxf(rmax, __shfl_xor(rmax, 1));
            rmax = fmaxf(rmax, __shfl_xor(rmax, 2));
            rmax = fmaxf(rmax, __shfl_xor(rmax, 4));
            rmax = fmaxf(rmax, __shfl_xor(rmax, 8));
            const float mnew = fmaxf(mst[r], rmax);
            float rsum = 0.f;
#pragma unroll
            for (int nt = 0; nt < 4; nt++) {
                const float pv = __expf(pb[nt][r] - mnew);
                pb[nt][r] = pv;
                rsum += pv;
            }
            rsum += __shfl_xor(rsum, 1);
            rsum += __shfl_xor(rsum, 2);
            rsum += __shfl_xor(rsum, 4);
            rsum += __shfl_xor(rsum, 8);
            const float alpha = __expf(mst[r] - mnew);
            mst[r] = mnew;
            lst[r] = lst[r] * alpha + rsum;
#pragma unroll
            for (int dt = 0; dt < 8; dt++) accO[dt][r] *= alpha;
        }

        // P (C/D layout) -> per-wave LDS (XOR-swizzled) -> A-operand layout.
        // slot(row,col) = row*64 + ((col>>3)^(row&7))*8 + (col&7): write 2-way.
        ushort_t* Pw = Ps + wave * 1024;
#pragma unroll
        for (int r = 0; r < 4; r++) {
            const int row = qd * 4 + r;
#pragma unroll
            for (int nt = 0; nt < 4; nt++) {
                const int col = nt * 16 + la;
                Pw[row * 64 + ((col >> 3) ^ (row & 7)) * 8 + (col & 7)] = f2bf(pb[nt][r]);
            }
        }

        // O += P V
#pragma unroll
        for (int k2 = 0; k2 < 2; k2++) {
            short8 pa = *(const short8*)&Pw[la * 64 + ((k2 * 4 + qd) ^ (la & 7)) * 8];
#pragma unroll
            for (int dt = 0; dt < 8; dt++) {
                const int d = dt * 16 + la;
                short8 vbf = *(const short8*)&Vt[d * 64 + ((k2 * 4 + qd) ^ (d & 7)) * 8];
                accO[dt] = MFMA16x16x32(pa, vbf, accO[dt]);
            }
        }
    }

    // Normalize and store [B*S, 2048] bf16
    const size_t orow0 = (size_t)b * 2048 + qt * 64 + wave * 16 + qd * 4;
#pragma unroll
    for (int r = 0; r < 4; r++) {
        const float inv = 1.f / lst[r];
#pragma unroll
        for (int dt = 0; dt < 8; dt++)
            out[(orow0 + r) * 2048 + h * 128 + dt * 16 + la] = f2bf(accO[dt][r] * inv);
    }
}

// ---------------------------------------------------------------------------
extern "C" void kernel_launch(void* const* d_in, const int* in_sizes, int n_in,
                              void* d_out, int out_size, void* d_ws, size_t ws_size,
                              hipStream_t stream) {
    (void)in_sizes; (void)n_in; (void)out_size; (void)ws_size;
    const float* x      = (const float*)d_in[0];
    const float* ln1w   = (const float*)d_in[1];
    const float* ln1b   = (const float*)d_in[2];
    const float* Wqkv   = (const float*)d_in[3];
    const float* bqkv   = (const float*)d_in[4];
    const float* Wo     = (const float*)d_in[5];
    const float* bo     = (const float*)d_in[6];
    const float* ln2w   = (const float*)d_in[7];
    const float* ln2b   = (const float*)d_in[8];
    const float* W1     = (const float*)d_in[9];
    const float* b1     = (const float*)d_in[10];
    const float* W2     = (const float*)d_in[11];
    const float* b2     = (const float*)d_in[12];
    const float* slopes = (const float*)d_in[13];
    float* outp = (float*)d_out;

    char* ws = (char*)d_ws;
    const size_t MB = 1ull << 20;
    // Workspace (~229 MB):
    //   [0,36MB)     wbuf    bf16, rotating big-weight region (Wqkv/Wo/W1/W2)
    //   [36,37MB)    small   bf16 vectors
    //   [37,69MB)    h_buf   bf16 [8192,2048]
    //   [69,197MB)   act     bf16: qkv [8192,6144] @+0, attn [8192,2048] @+96MB,
    //                              then act [8192,8192] @+0
    //   [197,229MB)  x2      bf16 [8192,2048]
    ushort_t* wbuf  = (ushort_t*)(ws);
    ushort_t* sv    = (ushort_t*)(ws + 36 * MB);
    ushort_t* ln1w_c = sv;            // 2048
    ushort_t* ln1b_c = sv + 2048;     // 2048
    ushort_t* bqkv_c = sv + 4096;     // 6144
    ushort_t* bo_c   = sv + 10240;    // 2048
    ushort_t* ln2w_c = sv + 12288;    // 2048
    ushort_t* ln2b_c = sv + 14336;    // 2048
    ushort_t* b1_c   = sv + 16384;    // 8192
    ushort_t* b2_c   = sv + 24576;    // 2048
    ushort_t* h_buf    = (ushort_t*)(ws + 37 * MB);
    ushort_t* qkv_buf  = (ushort_t*)(ws + 69 * MB);
    ushort_t* act_buf  = qkv_buf;
    ushort_t* attn_buf = (ushort_t*)(ws + 165 * MB);
    ushort_t* x2_buf   = (ushort_t*)(ws + 197 * MB);

    const int M = 8192;  // B*S

    // ---- LN1(x) -> h ----
    conv_bf16<<<8, 256, 0, stream>>>(ln1w, ln1w_c, 2048 / 8);
    conv_bf16<<<8, 256, 0, stream>>>(ln1b, ln1b_c, 2048 / 8);
    ln_kernel<1><<<M, 256, 0, stream>>>(x, ln1w_c, ln1b_c, h_buf);
    // ---- QKV GEMM (Q pre-scaled by 1/sqrt(128) in epilogue) ----
    conv_bf16<<<2048, 256, 0, stream>>>(Wqkv, wbuf, (6144 * 2048) / 8);
    conv_bf16<<<8, 256, 0, stream>>>(bqkv, bqkv_c, 6144 / 8);
    gemm_bt<0><<<(M / 128) * (6144 / 128), 256, 0, stream>>>(
        h_buf, wbuf, bqkv_c, nullptr, qkv_buf, M, 6144, 2048);
    // ---- Attention ----
    attn_kernel<<<dim3(32, 16, 4), 256, 0, stream>>>(qkv_buf, slopes, attn_buf);
    // ---- Out-proj + residual -> x2 (bf16) ----
    conv_bf16<<<1024, 256, 0, stream>>>(Wo, wbuf, (2048 * 2048) / 8);
    conv_bf16<<<8, 256, 0, stream>>>(bo, bo_c, 2048 / 8);
    gemm_bt<1><<<(M / 128) * (2048 / 128), 256, 0, stream>>>(
        attn_buf, wbuf, bo_c, x, x2_buf, M, 2048, 2048);
    // ---- LN2(x2) -> h ----
    conv_bf16<<<8, 256, 0, stream>>>(ln2w, ln2w_c, 2048 / 8);
    conv_bf16<<<8, 256, 0, stream>>>(ln2b, ln2b_c, 2048 / 8);
    ln_kernel<0><<<M, 256, 0, stream>>>(x2_buf, ln2w_c, ln2b_c, h_buf);
    // ---- MLP up + GELU ----
    conv_bf16<<<2048, 256, 0, stream>>>(W1, wbuf, (8192 * 2048) / 8);
    conv_bf16<<<8, 256, 0, stream>>>(b1, b1_c, 8192 / 8);
    gemm_bt<2><<<(M / 128) * (8192 / 128), 256, 0, stream>>>(
        h_buf, wbuf, b1_c, nullptr, act_buf, M, 8192, 2048);
    // ---- MLP down + residual -> out (fp32) ----
    conv_bf16<<<2048, 256, 0, stream>>>(W2, wbuf, (2048 * 8192) / 8);
    conv_bf16<<<8, 256, 0, stream>>>(b2, b2_c, 2048 / 8);
    gemm_bt<3><<<(M / 128) * (2048 / 128), 256, 0, stream>>>(
        act_buf, wbuf, b2_c, x2_buf, outp, M, 2048, 8192);
}

// Round 4
// 1834.597 us; speedup vs baseline: 1.2717x; 1.2717x over previous
//
#include <hip/hip_runtime.h>

typedef unsigned short ushort_t;
typedef __attribute__((ext_vector_type(8))) short short8;
typedef __attribute__((ext_vector_type(4))) float floatx4;
typedef __attribute__((ext_vector_type(4))) unsigned short ush4;

#define MFMA16x16x32(a, b, c) __builtin_amdgcn_mfma_f32_16x16x32_bf16(a, b, c, 0, 0, 0)

__device__ __forceinline__ float bf2f(ushort_t h) {
    unsigned int u = ((unsigned int)h) << 16;
    return __builtin_bit_cast(float, u);
}
__device__ __forceinline__ ushort_t f2bf(float f) {
    unsigned int u = __builtin_bit_cast(unsigned int, f);
    u += 0x7fffu + ((u >> 16) & 1u);
    return (ushort_t)(u >> 16);
}
__device__ __forceinline__ void gload_lds16(const ushort_t* g, ushort_t* l) {
    __builtin_amdgcn_global_load_lds(
        (const __attribute__((address_space(1))) unsigned int*)g,
        (__attribute__((address_space(3))) unsigned int*)l, 16, 0, 0);
}

// ---------------------------------------------------------------------------
// fp32 -> bf16 (RNE) conversion, 8 elems/thread, grid-stride.
// ---------------------------------------------------------------------------
__global__ __launch_bounds__(256) void conv_bf16(const float* __restrict__ in,
                                                 ushort_t* __restrict__ out, int n8) {
    int i = blockIdx.x * 256 + threadIdx.x;
    const int stride = gridDim.x * 256;
    for (; i < n8; i += stride) {
        const float* p = in + (size_t)i * 8;
        floatx4 a0 = *(const floatx4*)p;
        floatx4 a1 = *(const floatx4*)(p + 4);
        short8 o;
        o[0] = (short)f2bf(a0[0]); o[1] = (short)f2bf(a0[1]);
        o[2] = (short)f2bf(a0[2]); o[3] = (short)f2bf(a0[3]);
        o[4] = (short)f2bf(a1[0]); o[5] = (short)f2bf(a1[1]);
        o[6] = (short)f2bf(a1[2]); o[7] = (short)f2bf(a1[3]);
        *(short8*)(out + (size_t)i * 8) = o;
    }
}

// ---------------------------------------------------------------------------
// LayerNorm: one block per row of 2048. INF32=1: fp32 input (original x),
// INF32=0: bf16 input (x2 residual buffer). Params bf16, output bf16.
// ---------------------------------------------------------------------------
template <int INF32>
__global__ __launch_bounds__(256) void ln_kernel(const void* __restrict__ in,
                                                 const ushort_t* __restrict__ w,
                                                 const ushort_t* __restrict__ b,
                                                 ushort_t* __restrict__ out) {
    const int row = blockIdx.x;
    const int tid = threadIdx.x;
    const size_t base = (size_t)row * 2048 + (size_t)tid * 8;
    float v[8];
    if (INF32) {
        const float* p = (const float*)in + base;
        floatx4 a0 = *(const floatx4*)p;
        floatx4 a1 = *(const floatx4*)(p + 4);
        v[0] = a0[0]; v[1] = a0[1]; v[2] = a0[2]; v[3] = a0[3];
        v[4] = a1[0]; v[5] = a1[1]; v[6] = a1[2]; v[7] = a1[3];
    } else {
        short8 hv = *(const short8*)((const ushort_t*)in + base);
        const ushort_t* hp = (const ushort_t*)&hv;
#pragma unroll
        for (int k = 0; k < 8; k++) v[k] = bf2f(hp[k]);
    }
    float s = 0.f, sq = 0.f;
#pragma unroll
    for (int k = 0; k < 8; k++) { s += v[k]; sq += v[k] * v[k]; }
#pragma unroll
    for (int m = 32; m; m >>= 1) { s += __shfl_xor(s, m); sq += __shfl_xor(sq, m); }
    __shared__ float red[8];
    const int wv = tid >> 6;
    if ((tid & 63) == 0) { red[wv] = s; red[4 + wv] = sq; }
    __syncthreads();
    s = red[0] + red[1] + red[2] + red[3];
    sq = red[4] + red[5] + red[6] + red[7];
    const float mu = s * (1.f / 2048.f);
    const float var = fmaxf(sq * (1.f / 2048.f) - mu * mu, 0.f);
    const float rs = rsqrtf(var + 1e-5f);
    short8 ov;
#pragma unroll
    for (int k = 0; k < 8; k++) {
        const int c = tid * 8 + k;
        float y = (v[k] - mu) * rs * bf2f(w[c]) + bf2f(b[c]);
        ov[k] = (short)f2bf(y);
    }
    *(short8*)(out + base) = ov;
}

// ---------------------------------------------------------------------------
// GEMM: C[M,N] = A[M,K] * W[N,K]^T + bias (A,W,bias bf16), fused epilogues.
// m97 structure: 128x128 tile, BK=32, 256 thr (4 waves, 2x2 of 64x64),
// global_load_lds width-16 staging, 16x16x32 bf16 MFMA.
// EPI 0: QKV split-store: Q (pre-scaled 1/sqrt(128)) -> out[0,32MB),
//        K -> out+16M shorts, V TRANSPOSED [b,h,d][s] -> out+32M shorts
// EPI 1: +bias +fp32 residual -> bf16 out         (attn out-proj -> x2)
// EPI 2: +bias, exact GELU -> bf16 out            (MLP up)
// EPI 3: +bias +bf16 residual -> FP32 out         (MLP down -> final output)
// ---------------------------------------------------------------------------
template <int EPI>
__global__ __launch_bounds__(256) void gemm_bt(const ushort_t* __restrict__ A,
                                               const ushort_t* __restrict__ W,
                                               const ushort_t* __restrict__ bias,
                                               const void* __restrict__ res,
                                               void* __restrict__ out,
                                               int M, int N, int K) {
    __shared__ ushort_t As[4096];  // [128][32]
    __shared__ ushort_t Bs[4096];  // [128][32]
    const int tid = threadIdx.x;
    const int lane = tid & 63;
    const int wave = tid >> 6;
    const int nbn = N >> 7;
    const int bm = blockIdx.x / nbn;
    const int bn = blockIdx.x % nbn;
    const int wm = (wave >> 1) * 64;
    const int wn = (wave & 1) * 64;
    const int la = lane & 15;
    const int qd = lane >> 4;

    floatx4 acc[4][4];
    const floatx4 z4 = {0.f, 0.f, 0.f, 0.f};
#pragma unroll
    for (int i = 0; i < 4; i++)
#pragma unroll
        for (int j = 0; j < 4; j++) acc[i][j] = z4;

    const ushort_t* ga = A + (size_t)(bm * 128 + (tid >> 2)) * K + (tid & 3) * 8;
    const ushort_t* gb = W + (size_t)(bn * 128 + (tid >> 2)) * K + (tid & 3) * 8;
    ushort_t* lA = As + (size_t)(tid & ~63) * 8;
    ushort_t* lB = Bs + (size_t)(tid & ~63) * 8;
    const size_t strideR = (size_t)64 * K;

    for (int kt = 0; kt < K; kt += 32) {
        __syncthreads();
        gload_lds16(ga + kt, lA);
        gload_lds16(ga + kt + strideR, lA + 2048);
        gload_lds16(gb + kt, lB);
        gload_lds16(gb + kt + strideR, lB + 2048);
        __syncthreads();
        short8 af[4], bfr[4];
#pragma unroll
        for (int i = 0; i < 4; i++) af[i] = *(const short8*)&As[(wm + i * 16 + la) * 32 + qd * 8];
#pragma unroll
        for (int j = 0; j < 4; j++) bfr[j] = *(const short8*)&Bs[(wn + j * 16 + la) * 32 + qd * 8];
#pragma unroll
        for (int i = 0; i < 4; i++)
#pragma unroll
            for (int j = 0; j < 4; j++) acc[i][j] = MFMA16x16x32(af[i], bfr[j], acc[i][j]);
    }

    if (EPI == 0) {
        // QKV split epilogue (N=6144). bn<16: Q, bn<32: K, else V transposed.
        ushort_t* q_out = (ushort_t*)out;
        if (bn < 32) {
            const float qs = (bn < 16) ? 0.08838834764831845f : 1.0f;
            ushort_t* dst = (bn < 16) ? q_out : (q_out + 16777216);
#pragma unroll
            for (int i = 0; i < 4; i++)
#pragma unroll
                for (int j = 0; j < 4; j++)
#pragma unroll
                    for (int r = 0; r < 4; r++) {
                        const int m = bm * 128 + wm + i * 16 + qd * 4 + r;
                        const int n = bn * 128 + wn + j * 16 + la;
                        dst[(size_t)m * 2048 + (n & 2047)] =
                            f2bf((acc[i][j][r] + bf2f(bias[n])) * qs);
                    }
        } else {
            ushort_t* v_out = q_out + 33554432;
#pragma unroll
            for (int i = 0; i < 4; i++)
#pragma unroll
                for (int j = 0; j < 4; j++) {
                    const int n = bn * 128 + wn + j * 16 + la;   // 4096..6143
                    const int d = n - 4096;
                    const int m0 = bm * 128 + wm + i * 16 + qd * 4;
                    const int bb = m0 >> 11, s = m0 & 2047;
                    const float bv = bf2f(bias[n]);
                    ush4 pk;
#pragma unroll
                    for (int r = 0; r < 4; r++) pk[r] = f2bf(acc[i][j][r] + bv);
                    *(ush4*)&v_out[((size_t)(bb * 2048 + d)) * 2048 + s] = pk;
                }
        }
    } else {
#pragma unroll
        for (int i = 0; i < 4; i++)
#pragma unroll
            for (int j = 0; j < 4; j++)
#pragma unroll
                for (int r = 0; r < 4; r++) {
                    const int m = bm * 128 + wm + i * 16 + qd * 4 + r;
                    const int n = bn * 128 + wn + j * 16 + la;
                    const size_t idx = (size_t)m * N + n;
                    float v = acc[i][j][r] + bf2f(bias[n]);
                    if (EPI == 1) {
                        v += ((const float*)res)[idx];
                        ((ushort_t*)out)[idx] = f2bf(v);
                    } else if (EPI == 2) {
                        v = 0.5f * v * (1.f + erff(v * 0.70710678118654752f));
                        ((ushort_t*)out)[idx] = f2bf(v);
                    } else {
                        v += bf2f(((const ushort_t*)res)[idx]);
                        ((float*)out)[idx] = v;
                    }
                }
    }
}

// ---------------------------------------------------------------------------
// Flash attention, ALiBi + causal. One WG (256 thr) per (b, h, 64-row q-tile).
//   - Q pre-scaled; Q frags loaded global->registers (no LDS pass).
//   - K staged [64][128] and V^T staged [128][64] via global_load_lds w=16
//     with XOR-chunk source swizzle (frag reads 2-way conflict = free).
//   - V^T comes from the pre-transposed v buffer (no in-kernel transpose).
//   - ALiBi row term dropped (softmax-invariant); causal mask diag tile only.
//   - LDS 40960 B -> 4 WG/CU; ~90 VGPR (exp in place, no pb array).
// ---------------------------------------------------------------------------
__global__ __launch_bounds__(256, 4) void attn_kernel(const ushort_t* __restrict__ qb,
                                                      const ushort_t* __restrict__ kb,
                                                      const ushort_t* __restrict__ vtb,
                                                      const float* __restrict__ slopes,
                                                      ushort_t* __restrict__ out) {
    __shared__ ushort_t Ks[8192];   // [64 rows][16 chunks of 8]
    __shared__ ushort_t Vt[8192];   // [128 d-rows][8 chunks of 8]
    __shared__ ushort_t Ps[4096];   // 4 waves x [16][64] XOR-swizzled
    const int tid = threadIdx.x;
    const int lane = tid & 63;
    const int wave = tid >> 6;
    const int la = lane & 15;
    const int qd = lane >> 4;
    const int qt = blockIdx.x;
    const int h = blockIdx.y;
    const int b = blockIdx.z;
    const float slope = slopes[h];

    // Q fragments straight from global (one-time).
    const size_t qrow = (size_t)(b * 2048 + qt * 64 + wave * 16 + la);
    short8 qa[4];
#pragma unroll
    for (int ks = 0; ks < 4; ks++)
        qa[ks] = *(const short8*)&qb[qrow * 2048 + h * 128 + (ks * 4 + qd) * 8];

    const ushort_t* kbase = kb + ((size_t)b * 2048) * 2048 + h * 128;
    const ushort_t* vbase = vtb + ((size_t)(b * 2048 + h * 128)) * 2048;

    floatx4 accO[8];
    const floatx4 z4 = {0.f, 0.f, 0.f, 0.f};
#pragma unroll
    for (int dt = 0; dt < 8; dt++) accO[dt] = z4;
    float mst[4] = {-1e30f, -1e30f, -1e30f, -1e30f};
    float lst[4] = {0.f, 0.f, 0.f, 0.f};

    for (int kt = 0; kt <= qt; kt++) {
        __syncthreads();  // all waves done reading Ks/Vt of prev tile
        // K tile: slot f=(r,cs) holds global chunk cs^(r&15).
#pragma unroll
        for (int p = 0; p < 4; p++) {
            const int f = p * 256 + tid;
            const int r = f >> 4;
            const int cs = f & 15;
            gload_lds16(kbase + (size_t)(kt * 64 + r) * 2048 + (cs ^ (r & 15)) * 8,
                        Ks + (size_t)(p * 256 + (tid & ~63)) * 8);
        }
        // V^T tile: slot f=(d,c) holds global s-chunk c^(d&7).
#pragma unroll
        for (int p = 0; p < 4; p++) {
            const int f = p * 256 + tid;
            const int d = f >> 3;
            const int c = f & 7;
            gload_lds16(vbase + (size_t)d * 2048 + kt * 64 + (c ^ (d & 7)) * 8,
                        Vt + (size_t)(p * 256 + (tid & ~63)) * 8);
        }
        __syncthreads();

        // S = (Q/sqrt(d)) K^T  (per wave: 16 rows x 64 cols)
        floatx4 sc[4];
#pragma unroll
        for (int nt = 0; nt < 4; nt++) sc[nt] = z4;
#pragma unroll
        for (int nt = 0; nt < 4; nt++) {
#pragma unroll
            for (int ks = 0; ks < 4; ks++) {
                short8 kf = *(const short8*)&Ks[(nt * 16 + la) * 128 + ((ks * 4 + qd) ^ la) * 8];
                sc[nt] = MFMA16x16x32(qa[ks], kf, sc[nt]);
            }
        }

        // Online softmax; exp in place; P -> per-wave XOR-swizzled LDS.
        const int knb = kt * 64;
        const bool diag = (kt == qt);
        ushort_t* Pw = Ps + wave * 1024;
#pragma unroll
        for (int r = 0; r < 4; r++) {
            float rmax = -1e30f;
#pragma unroll
            for (int nt = 0; nt < 4; nt++) {
                float sval = sc[nt][r] + slope * (float)(knb + nt * 16 + la);
                if (diag && (nt * 16 + la > wave * 16 + qd * 4 + r)) sval = -1e30f;
                sc[nt][r] = sval;
                rmax = fmaxf(rmax, sval);
            }
            rmax = fmaxf(rmax, __shfl_xor(rmax, 1));
            rmax = fmaxf(rmax, __shfl_xor(rmax, 2));
            rmax = fmaxf(rmax, __shfl_xor(rmax, 4));
            rmax = fmaxf(rmax, __shfl_xor(rmax, 8));
            const float mnew = fmaxf(mst[r], rmax);
            const int row = qd * 4 + r;
            float rsum = 0.f;
#pragma unroll
            for (int nt = 0; nt < 4; nt++) {
                const float pv = __expf(sc[nt][r] - mnew);
                rsum += pv;
                const int col = nt * 16 + la;
                Pw[row * 64 + ((col >> 3) ^ (row & 7)) * 8 + (col & 7)] = f2bf(pv);
            }
            rsum += __shfl_xor(rsum, 1);
            rsum += __shfl_xor(rsum, 2);
            rsum += __shfl_xor(rsum, 4);
            rsum += __shfl_xor(rsum, 8);
            const float alpha = __expf(mst[r] - mnew);
            mst[r] = mnew;
            lst[r] = lst[r] * alpha + rsum;
#pragma unroll
            for (int dt = 0; dt < 8; dt++) accO[dt][r] *= alpha;
        }

        // O += P V
#pragma unroll
        for (int k2 = 0; k2 < 2; k2++) {
            short8 pa = *(const short8*)&Pw[la * 64 + ((k2 * 4 + qd) ^ (la & 7)) * 8];
#pragma unroll
            for (int dt = 0; dt < 8; dt++) {
                const int d = dt * 16 + la;
                short8 vf = *(const short8*)&Vt[d * 64 + ((k2 * 4 + qd) ^ (d & 7)) * 8];
                accO[dt] = MFMA16x16x32(pa, vf, accO[dt]);
            }
        }
    }

    // Normalize and store [B*S, 2048] bf16
    const size_t orow0 = (size_t)b * 2048 + qt * 64 + wave * 16 + qd * 4;
#pragma unroll
    for (int r = 0; r < 4; r++) {
        const float inv = 1.f / lst[r];
#pragma unroll
        for (int dt = 0; dt < 8; dt++)
            out[(orow0 + r) * 2048 + h * 128 + dt * 16 + la] = f2bf(accO[dt][r] * inv);
    }
}

// ---------------------------------------------------------------------------
extern "C" void kernel_launch(void* const* d_in, const int* in_sizes, int n_in,
                              void* d_out, int out_size, void* d_ws, size_t ws_size,
                              hipStream_t stream) {
    (void)in_sizes; (void)n_in; (void)out_size; (void)ws_size;
    const float* x      = (const float*)d_in[0];
    const float* ln1w   = (const float*)d_in[1];
    const float* ln1b   = (const float*)d_in[2];
    const float* Wqkv   = (const float*)d_in[3];
    const float* bqkv   = (const float*)d_in[4];
    const float* Wo     = (const float*)d_in[5];
    const float* bo     = (const float*)d_in[6];
    const float* ln2w   = (const float*)d_in[7];
    const float* ln2b   = (const float*)d_in[8];
    const float* W1     = (const float*)d_in[9];
    const float* b1     = (const float*)d_in[10];
    const float* W2     = (const float*)d_in[11];
    const float* b2     = (const float*)d_in[12];
    const float* slopes = (const float*)d_in[13];
    float* outp = (float*)d_out;

    char* ws = (char*)d_ws;
    const size_t MB = 1ull << 20;
    // Workspace (~229 MB):
    //   [0,36MB)     wbuf  bf16 rotating big-weight region
    //   [36,37MB)    small bf16 vectors
    //   [37,69MB)    h_buf bf16 [8192,2048]
    //   [69,197MB)   q@69 k@101 vt@133 attn@165 (attn phase)
    //                act [8192,8192] @69 (MLP phase, aliases all four)
    //   [197,229MB)  x2    bf16 [8192,2048]
    ushort_t* wbuf  = (ushort_t*)(ws);
    ushort_t* sv    = (ushort_t*)(ws + 36 * MB);
    ushort_t* ln1w_c = sv;            // 2048
    ushort_t* ln1b_c = sv + 2048;     // 2048
    ushort_t* bqkv_c = sv + 4096;     // 6144
    ushort_t* bo_c   = sv + 10240;    // 2048
    ushort_t* ln2w_c = sv + 12288;    // 2048
    ushort_t* ln2b_c = sv + 14336;    // 2048
    ushort_t* b1_c   = sv + 16384;    // 8192
    ushort_t* b2_c   = sv + 24576;    // 2048
    ushort_t* h_buf    = (ushort_t*)(ws + 37 * MB);
    ushort_t* q_buf    = (ushort_t*)(ws + 69 * MB);
    ushort_t* k_buf    = (ushort_t*)(ws + 101 * MB);
    ushort_t* vt_buf   = (ushort_t*)(ws + 133 * MB);
    ushort_t* attn_buf = (ushort_t*)(ws + 165 * MB);
    ushort_t* act_buf  = q_buf;
    ushort_t* x2_buf   = (ushort_t*)(ws + 197 * MB);

    const int M = 8192;  // B*S

    // ---- LN1(x) -> h ----
    conv_bf16<<<8, 256, 0, stream>>>(ln1w, ln1w_c, 2048 / 8);
    conv_bf16<<<8, 256, 0, stream>>>(ln1b, ln1b_c, 2048 / 8);
    ln_kernel<1><<<M, 256, 0, stream>>>(x, ln1w_c, ln1b_c, h_buf);
    // ---- QKV GEMM (split q/k/vt store; Q pre-scaled) ----
    conv_bf16<<<2048, 256, 0, stream>>>(Wqkv, wbuf, (6144 * 2048) / 8);
    conv_bf16<<<8, 256, 0, stream>>>(bqkv, bqkv_c, 6144 / 8);
    gemm_bt<0><<<(M / 128) * (6144 / 128), 256, 0, stream>>>(
        h_buf, wbuf, bqkv_c, nullptr, q_buf, M, 6144, 2048);
    // ---- Attention ----
    attn_kernel<<<dim3(32, 16, 4), 256, 0, stream>>>(q_buf, k_buf, vt_buf, slopes, attn_buf);
    // ---- Out-proj + residual -> x2 (bf16) ----
    conv_bf16<<<1024, 256, 0, stream>>>(Wo, wbuf, (2048 * 2048) / 8);
    conv_bf16<<<8, 256, 0, stream>>>(bo, bo_c, 2048 / 8);
    gemm_bt<1><<<(M / 128) * (2048 / 128), 256, 0, stream>>>(
        attn_buf, wbuf, bo_c, x, x2_buf, M, 2048, 2048);
    // ---- LN2(x2) -> h ----
    conv_bf16<<<8, 256, 0, stream>>>(ln2w, ln2w_c, 2048 / 8);
    conv_bf16<<<8, 256, 0, stream>>>(ln2b, ln2b_c, 2048 / 8);
    ln_kernel<0><<<M, 256, 0, stream>>>(x2_buf, ln2w_c, ln2b_c, h_buf);
    // ---- MLP up + GELU ----
    conv_bf16<<<2048, 256, 0, stream>>>(W1, wbuf, (8192 * 2048) / 8);
    conv_bf16<<<8, 256, 0, stream>>>(b1, b1_c, 8192 / 8);
    gemm_bt<2><<<(M / 128) * (8192 / 128), 256, 0, stream>>>(
        h_buf, wbuf, b1_c, nullptr, act_buf, M, 8192, 2048);
    // ---- MLP down + residual -> out (fp32) ----
    conv_bf16<<<2048, 256, 0, stream>>>(W2, wbuf, (2048 * 8192) / 8);
    conv_bf16<<<8, 256, 0, stream>>>(b2, b2_c, 2048 / 8);
    gemm_bt<3><<<(M / 128) * (2048 / 128), 256, 0, stream>>>(
        act_buf, wbuf, b2_c, x2_buf, outp, M, 2048, 8192);
}

// Round 5
// 1689.605 us; speedup vs baseline: 1.3808x; 1.0858x over previous
//
#include <hip/hip_runtime.h>

typedef unsigned short ushort_t;
typedef __attribute__((ext_vector_type(8))) short short8;
typedef __attribute__((ext_vector_type(4))) float floatx4;
typedef __attribute__((ext_vector_type(4))) unsigned short ush4;

#define MFMA16x16x32(a, b, c) __builtin_amdgcn_mfma_f32_16x16x32_bf16(a, b, c, 0, 0, 0)

__device__ __forceinline__ float bf2f(ushort_t h) {
    unsigned int u = ((unsigned int)h) << 16;
    return __builtin_bit_cast(float, u);
}
__device__ __forceinline__ ushort_t f2bf(float f) {
    unsigned int u = __builtin_bit_cast(unsigned int, f);
    u += 0x7fffu + ((u >> 16) & 1u);
    return (ushort_t)(u >> 16);
}
__device__ __forceinline__ void gload_lds16(const ushort_t* g, ushort_t* l) {
    __builtin_amdgcn_global_load_lds(
        (const __attribute__((address_space(1))) unsigned int*)g,
        (__attribute__((address_space(3))) unsigned int*)l, 16, 0, 0);
}

// ---------------------------------------------------------------------------
// fp32 -> bf16 (RNE) conversion, 8 elems/thread, grid-stride.
// ---------------------------------------------------------------------------
__global__ __launch_bounds__(256) void conv_bf16(const float* __restrict__ in,
                                                 ushort_t* __restrict__ out, int n8) {
    int i = blockIdx.x * 256 + threadIdx.x;
    const int stride = gridDim.x * 256;
    for (; i < n8; i += stride) {
        const float* p = in + (size_t)i * 8;
        floatx4 a0 = *(const floatx4*)p;
        floatx4 a1 = *(const floatx4*)(p + 4);
        short8 o;
        o[0] = (short)f2bf(a0[0]); o[1] = (short)f2bf(a0[1]);
        o[2] = (short)f2bf(a0[2]); o[3] = (short)f2bf(a0[3]);
        o[4] = (short)f2bf(a1[0]); o[5] = (short)f2bf(a1[1]);
        o[6] = (short)f2bf(a1[2]); o[7] = (short)f2bf(a1[3]);
        *(short8*)(out + (size_t)i * 8) = o;
    }
}

// ---------------------------------------------------------------------------
// LayerNorm: one block per row of 2048. INF32=1: fp32 input (original x),
// INF32=0: bf16 input (x2 residual buffer). Params bf16, output bf16.
// ---------------------------------------------------------------------------
template <int INF32>
__global__ __launch_bounds__(256) void ln_kernel(const void* __restrict__ in,
                                                 const ushort_t* __restrict__ w,
                                                 const ushort_t* __restrict__ b,
                                                 ushort_t* __restrict__ out) {
    const int row = blockIdx.x;
    const int tid = threadIdx.x;
    const size_t base = (size_t)row * 2048 + (size_t)tid * 8;
    float v[8];
    if (INF32) {
        const float* p = (const float*)in + base;
        floatx4 a0 = *(const floatx4*)p;
        floatx4 a1 = *(const floatx4*)(p + 4);
        v[0] = a0[0]; v[1] = a0[1]; v[2] = a0[2]; v[3] = a0[3];
        v[4] = a1[0]; v[5] = a1[1]; v[6] = a1[2]; v[7] = a1[3];
    } else {
        short8 hv = *(const short8*)((const ushort_t*)in + base);
        const ushort_t* hp = (const ushort_t*)&hv;
#pragma unroll
        for (int k = 0; k < 8; k++) v[k] = bf2f(hp[k]);
    }
    float s = 0.f, sq = 0.f;
#pragma unroll
    for (int k = 0; k < 8; k++) { s += v[k]; sq += v[k] * v[k]; }
#pragma unroll
    for (int m = 32; m; m >>= 1) { s += __shfl_xor(s, m); sq += __shfl_xor(sq, m); }
    __shared__ float red[8];
    const int wv = tid >> 6;
    if ((tid & 63) == 0) { red[wv] = s; red[4 + wv] = sq; }
    __syncthreads();
    s = red[0] + red[1] + red[2] + red[3];
    sq = red[4] + red[5] + red[6] + red[7];
    const float mu = s * (1.f / 2048.f);
    const float var = fmaxf(sq * (1.f / 2048.f) - mu * mu, 0.f);
    const float rs = rsqrtf(var + 1e-5f);
    short8 ov;
#pragma unroll
    for (int k = 0; k < 8; k++) {
        const int c = tid * 8 + k;
        float y = (v[k] - mu) * rs * bf2f(w[c]) + bf2f(b[c]);
        ov[k] = (short)f2bf(y);
    }
    *(short8*)(out + base) = ov;
}

// ---------------------------------------------------------------------------
// GEMM: C[M,N] = A[M,K] * W[N,K]^T + bias (A,W,bias bf16), fused epilogues.
// 128x128 tile, BK=64 (32 MFMA per barrier), 256 thr (4 waves, 2x2 of 64x64),
// global_load_lds w=16 staging with XOR-chunk swizzle (slot c holds global
// chunk c^(r&7); frag reads span all 32 banks, 2-way alias = free),
// 8-row bm-group rasterization for L2 reuse. 16x16x32 bf16 MFMA.
// EPI 0: QKV split-store: Q (pre-scaled 1/sqrt(128)) -> out[0,32MB),
//        K -> out+16M shorts, V TRANSPOSED [b,h,d][s] -> out+32M shorts
// EPI 1: +bias +fp32 residual -> bf16 out         (attn out-proj -> x2)
// EPI 2: +bias, exact GELU -> bf16 out            (MLP up)
// EPI 3: +bias +bf16 residual -> FP32 out         (MLP down -> final output)
// ---------------------------------------------------------------------------
template <int EPI>
__global__ __launch_bounds__(256) void gemm_bt(const ushort_t* __restrict__ A,
                                               const ushort_t* __restrict__ W,
                                               const ushort_t* __restrict__ bias,
                                               const void* __restrict__ res,
                                               void* __restrict__ out,
                                               int M, int N, int K) {
    __shared__ ushort_t As[8192];  // [128][64] XOR-chunk-swizzled
    __shared__ ushort_t Bs[8192];
    const int tid = threadIdx.x;
    const int lane = tid & 63;
    const int wave = tid >> 6;
    const int nbn = N >> 7;
    // Rasterization: groups of 8 bm, bn-major within group (M=8192 -> nbm=64).
    int bm, bn;
    {
        const int per = 8 * nbn;
        const int g = blockIdx.x / per;
        const int rem = blockIdx.x % per;
        bm = g * 8 + (rem & 7);
        bn = rem >> 3;
    }
    const int wm = (wave >> 1) * 64;
    const int wn = (wave & 1) * 64;
    const int la = lane & 15;
    const int qd = lane >> 4;

    floatx4 acc[4][4];
    const floatx4 z4 = {0.f, 0.f, 0.f, 0.f};
#pragma unroll
    for (int i = 0; i < 4; i++)
#pragma unroll
        for (int j = 0; j < 4; j++) acc[i][j] = z4;

    // Staging map: round p covers flat chunks f = p*256 + tid; r=f>>3, cs=f&7.
    // LDS slot (r,cs) receives global chunk cs^(r&7); since p*32 ≡ 0 (mod 8),
    // the per-thread source column offset is constant across rounds.
    const int srow = tid >> 3;                       // 0..31, +p*32 per round
    const int schunk = (tid & 7) ^ ((tid >> 3) & 7); // gather permutation
    const ushort_t* ga = A + (size_t)(bm * 128 + srow) * K + schunk * 8;
    const ushort_t* gb = W + (size_t)(bn * 128 + srow) * K + schunk * 8;
    ushort_t* lA = As + (size_t)(tid & ~63) * 8;
    ushort_t* lB = Bs + (size_t)(tid & ~63) * 8;
    const size_t rowK32 = (size_t)32 * K;

    for (int kt = 0; kt < K; kt += 64) {
        __syncthreads();
#pragma unroll
        for (int p = 0; p < 4; p++) {
            gload_lds16(ga + kt + p * rowK32, lA + p * 2048);
            gload_lds16(gb + kt + p * rowK32, lB + p * 2048);
        }
        __syncthreads();
#pragma unroll
        for (int kh = 0; kh < 2; kh++) {
            short8 af[4], bfr[4];
#pragma unroll
            for (int i = 0; i < 4; i++)
                af[i] = *(const short8*)&As[(wm + i * 16 + la) * 64 +
                                            (((kh * 4 + qd) ^ (la & 7)) * 8)];
#pragma unroll
            for (int j = 0; j < 4; j++)
                bfr[j] = *(const short8*)&Bs[(wn + j * 16 + la) * 64 +
                                             (((kh * 4 + qd) ^ (la & 7)) * 8)];
#pragma unroll
            for (int i = 0; i < 4; i++)
#pragma unroll
                for (int j = 0; j < 4; j++) acc[i][j] = MFMA16x16x32(af[i], bfr[j], acc[i][j]);
        }
    }

    if (EPI == 0) {
        // QKV split epilogue (N=6144). bn<16: Q, bn<32: K, else V transposed.
        ushort_t* q_out = (ushort_t*)out;
        if (bn < 32) {
            const float qs = (bn < 16) ? 0.08838834764831845f : 1.0f;
            ushort_t* dst = (bn < 16) ? q_out : (q_out + 16777216);
#pragma unroll
            for (int i = 0; i < 4; i++)
#pragma unroll
                for (int j = 0; j < 4; j++)
#pragma unroll
                    for (int r = 0; r < 4; r++) {
                        const int m = bm * 128 + wm + i * 16 + qd * 4 + r;
                        const int n = bn * 128 + wn + j * 16 + la;
                        dst[(size_t)m * 2048 + (n & 2047)] =
                            f2bf((acc[i][j][r] + bf2f(bias[n])) * qs);
                    }
        } else {
            ushort_t* v_out = q_out + 33554432;
#pragma unroll
            for (int i = 0; i < 4; i++)
#pragma unroll
                for (int j = 0; j < 4; j++) {
                    const int n = bn * 128 + wn + j * 16 + la;   // 4096..6143
                    const int d = n - 4096;
                    const int m0 = bm * 128 + wm + i * 16 + qd * 4;
                    const int bb = m0 >> 11, s = m0 & 2047;
                    const float bv = bf2f(bias[n]);
                    ush4 pk;
#pragma unroll
                    for (int r = 0; r < 4; r++) pk[r] = f2bf(acc[i][j][r] + bv);
                    *(ush4*)&v_out[((size_t)(bb * 2048 + d)) * 2048 + s] = pk;
                }
        }
    } else {
#pragma unroll
        for (int i = 0; i < 4; i++)
#pragma unroll
            for (int j = 0; j < 4; j++)
#pragma unroll
                for (int r = 0; r < 4; r++) {
                    const int m = bm * 128 + wm + i * 16 + qd * 4 + r;
                    const int n = bn * 128 + wn + j * 16 + la;
                    const size_t idx = (size_t)m * N + n;
                    float v = acc[i][j][r] + bf2f(bias[n]);
                    if (EPI == 1) {
                        v += ((const float*)res)[idx];
                        ((ushort_t*)out)[idx] = f2bf(v);
                    } else if (EPI == 2) {
                        v = 0.5f * v * (1.f + erff(v * 0.70710678118654752f));
                        ((ushort_t*)out)[idx] = f2bf(v);
                    } else {
                        v += bf2f(((const ushort_t*)res)[idx]);
                        ((float*)out)[idx] = v;
                    }
                }
    }
}

// ---------------------------------------------------------------------------
// Flash attention, ALiBi + causal. One WG (256 thr) per (b, h, 64-row q-tile).
//   - Q pre-scaled; Q frags loaded global->registers (no LDS pass).
//   - K staged [64][128] and V^T staged [128][64] via global_load_lds w=16
//     with XOR-chunk source swizzle (frag reads 2-way conflict = free).
//   - V^T comes from the pre-transposed v buffer (no in-kernel transpose).
//   - ALiBi row term dropped (softmax-invariant); causal mask diag tile only.
//   - LDS 40960 B -> 4 WG/CU.
// ---------------------------------------------------------------------------
__global__ __launch_bounds__(256, 4) void attn_kernel(const ushort_t* __restrict__ qb,
                                                      const ushort_t* __restrict__ kb,
                                                      const ushort_t* __restrict__ vtb,
                                                      const float* __restrict__ slopes,
                                                      ushort_t* __restrict__ out) {
    __shared__ ushort_t Ks[8192];   // [64 rows][16 chunks of 8]
    __shared__ ushort_t Vt[8192];   // [128 d-rows][8 chunks of 8]
    __shared__ ushort_t Ps[4096];   // 4 waves x [16][64] XOR-swizzled
    const int tid = threadIdx.x;
    const int lane = tid & 63;
    const int wave = tid >> 6;
    const int la = lane & 15;
    const int qd = lane >> 4;
    const int qt = blockIdx.x;
    const int h = blockIdx.y;
    const int b = blockIdx.z;
    const float slope = slopes[h];

    // Q fragments straight from global (one-time).
    const size_t qrow = (size_t)(b * 2048 + qt * 64 + wave * 16 + la);
    short8 qa[4];
#pragma unroll
    for (int ks = 0; ks < 4; ks++)
        qa[ks] = *(const short8*)&qb[qrow * 2048 + h * 128 + (ks * 4 + qd) * 8];

    const ushort_t* kbase = kb + ((size_t)b * 2048) * 2048 + h * 128;
    const ushort_t* vbase = vtb + ((size_t)(b * 2048 + h * 128)) * 2048;

    floatx4 accO[8];
    const floatx4 z4 = {0.f, 0.f, 0.f, 0.f};
#pragma unroll
    for (int dt = 0; dt < 8; dt++) accO[dt] = z4;
    float mst[4] = {-1e30f, -1e30f, -1e30f, -1e30f};
    float lst[4] = {0.f, 0.f, 0.f, 0.f};

    for (int kt = 0; kt <= qt; kt++) {
        __syncthreads();  // all waves done reading Ks/Vt of prev tile
        // K tile: slot f=(r,cs) holds global chunk cs^(r&15).
#pragma unroll
        for (int p = 0; p < 4; p++) {
            const int f = p * 256 + tid;
            const int r = f >> 4;
            const int cs = f & 15;
            gload_lds16(kbase + (size_t)(kt * 64 + r) * 2048 + (cs ^ (r & 15)) * 8,
                        Ks + (size_t)(p * 256 + (tid & ~63)) * 8);
        }
        // V^T tile: slot f=(d,c) holds global s-chunk c^(d&7).
#pragma unroll
        for (int p = 0; p < 4; p++) {
            const int f = p * 256 + tid;
            const int d = f >> 3;
            const int c = f & 7;
            gload_lds16(vbase + (size_t)d * 2048 + kt * 64 + (c ^ (d & 7)) * 8,
                        Vt + (size_t)(p * 256 + (tid & ~63)) * 8);
        }
        __syncthreads();

        // S = (Q/sqrt(d)) K^T  (per wave: 16 rows x 64 cols)
        floatx4 sc[4];
#pragma unroll
        for (int nt = 0; nt < 4; nt++) sc[nt] = z4;
#pragma unroll
        for (int nt = 0; nt < 4; nt++) {
#pragma unroll
            for (int ks = 0; ks < 4; ks++) {
                short8 kf = *(const short8*)&Ks[(nt * 16 + la) * 128 + ((ks * 4 + qd) ^ la) * 8];
                sc[nt] = MFMA16x16x32(qa[ks], kf, sc[nt]);
            }
        }

        // Online softmax; exp in place; P -> per-wave XOR-swizzled LDS.
        const int knb = kt * 64;
        const bool diag = (kt == qt);
        ushort_t* Pw = Ps + wave * 1024;
#pragma unroll
        for (int r = 0; r < 4; r++) {
            float rmax = -1e30f;
#pragma unroll
            for (int nt = 0; nt < 4; nt++) {
                float sval = sc[nt][r] + slope * (float)(knb + nt * 16 + la);
                if (diag && (nt * 16 + la > wave * 16 + qd * 4 + r)) sval = -1e30f;
                sc[nt][r] = sval;
                rmax = fmaxf(rmax, sval);
            }
            rmax = fmaxf(rmax, __shfl_xor(rmax, 1));
            rmax = fmaxf(rmax, __shfl_xor(rmax, 2));
            rmax = fmaxf(rmax, __shfl_xor(rmax, 4));
            rmax = fmaxf(rmax, __shfl_xor(rmax, 8));
            const float mnew = fmaxf(mst[r], rmax);
            const int row = qd * 4 + r;
            float rsum = 0.f;
#pragma unroll
            for (int nt = 0; nt < 4; nt++) {
                const float pv = __expf(sc[nt][r] - mnew);
                rsum += pv;
                const int col = nt * 16 + la;
                Pw[row * 64 + ((col >> 3) ^ (row & 7)) * 8 + (col & 7)] = f2bf(pv);
            }
            rsum += __shfl_xor(rsum, 1);
            rsum += __shfl_xor(rsum, 2);
            rsum += __shfl_xor(rsum, 4);
            rsum += __shfl_xor(rsum, 8);
            const float alpha = __expf(mst[r] - mnew);
            mst[r] = mnew;
            lst[r] = lst[r] * alpha + rsum;
#pragma unroll
            for (int dt = 0; dt < 8; dt++) accO[dt][r] *= alpha;
        }

        // O += P V
#pragma unroll
        for (int k2 = 0; k2 < 2; k2++) {
            short8 pa = *(const short8*)&Pw[la * 64 + ((k2 * 4 + qd) ^ (la & 7)) * 8];
#pragma unroll
            for (int dt = 0; dt < 8; dt++) {
                const int d = dt * 16 + la;
                short8 vf = *(const short8*)&Vt[d * 64 + ((k2 * 4 + qd) ^ (d & 7)) * 8];
                accO[dt] = MFMA16x16x32(pa, vf, accO[dt]);
            }
        }
    }

    // Normalize and store [B*S, 2048] bf16
    const size_t orow0 = (size_t)b * 2048 + qt * 64 + wave * 16 + qd * 4;
#pragma unroll
    for (int r = 0; r < 4; r++) {
        const float inv = 1.f / lst[r];
#pragma unroll
        for (int dt = 0; dt < 8; dt++)
            out[(orow0 + r) * 2048 + h * 128 + dt * 16 + la] = f2bf(accO[dt][r] * inv);
    }
}

// ---------------------------------------------------------------------------
extern "C" void kernel_launch(void* const* d_in, const int* in_sizes, int n_in,
                              void* d_out, int out_size, void* d_ws, size_t ws_size,
                              hipStream_t stream) {
    (void)in_sizes; (void)n_in; (void)out_size; (void)ws_size;
    const float* x      = (const float*)d_in[0];
    const float* ln1w   = (const float*)d_in[1];
    const float* ln1b   = (const float*)d_in[2];
    const float* Wqkv   = (const float*)d_in[3];
    const float* bqkv   = (const float*)d_in[4];
    const float* Wo     = (const float*)d_in[5];
    const float* bo     = (const float*)d_in[6];
    const float* ln2w   = (const float*)d_in[7];
    const float* ln2b   = (const float*)d_in[8];
    const float* W1     = (const float*)d_in[9];
    const float* b1     = (const float*)d_in[10];
    const float* W2     = (const float*)d_in[11];
    const float* b2     = (const float*)d_in[12];
    const float* slopes = (const float*)d_in[13];
    float* outp = (float*)d_out;

    char* ws = (char*)d_ws;
    const size_t MB = 1ull << 20;
    // Workspace (~229 MB):
    //   [0,36MB)     wbuf  bf16 rotating big-weight region
    //   [36,37MB)    small bf16 vectors
    //   [37,69MB)    h_buf bf16 [8192,2048]
    //   [69,197MB)   q@69 k@101 vt@133 attn@165 (attn phase)
    //                act [8192,8192] @69 (MLP phase, aliases all four)
    //   [197,229MB)  x2    bf16 [8192,2048]
    ushort_t* wbuf  = (ushort_t*)(ws);
    ushort_t* sv    = (ushort_t*)(ws + 36 * MB);
    ushort_t* ln1w_c = sv;            // 2048
    ushort_t* ln1b_c = sv + 2048;     // 2048
    ushort_t* bqkv_c = sv + 4096;     // 6144
    ushort_t* bo_c   = sv + 10240;    // 2048
    ushort_t* ln2w_c = sv + 12288;    // 2048
    ushort_t* ln2b_c = sv + 14336;    // 2048
    ushort_t* b1_c   = sv + 16384;    // 8192
    ushort_t* b2_c   = sv + 24576;    // 2048
    ushort_t* h_buf    = (ushort_t*)(ws + 37 * MB);
    ushort_t* q_buf    = (ushort_t*)(ws + 69 * MB);
    ushort_t* k_buf    = (ushort_t*)(ws + 101 * MB);
    ushort_t* vt_buf   = (ushort_t*)(ws + 133 * MB);
    ushort_t* attn_buf = (ushort_t*)(ws + 165 * MB);
    ushort_t* act_buf  = q_buf;
    ushort_t* x2_buf   = (ushort_t*)(ws + 197 * MB);

    const int M = 8192;  // B*S

    // ---- LN1(x) -> h ----
    conv_bf16<<<8, 256, 0, stream>>>(ln1w, ln1w_c, 2048 / 8);
    conv_bf16<<<8, 256, 0, stream>>>(ln1b, ln1b_c, 2048 / 8);
    ln_kernel<1><<<M, 256, 0, stream>>>(x, ln1w_c, ln1b_c, h_buf);
    // ---- QKV GEMM (split q/k/vt store; Q pre-scaled) ----
    conv_bf16<<<2048, 256, 0, stream>>>(Wqkv, wbuf, (6144 * 2048) / 8);
    conv_bf16<<<8, 256, 0, stream>>>(bqkv, bqkv_c, 6144 / 8);
    gemm_bt<0><<<(M / 128) * (6144 / 128), 256, 0, stream>>>(
        h_buf, wbuf, bqkv_c, nullptr, q_buf, M, 6144, 2048);
    // ---- Attention ----
    attn_kernel<<<dim3(32, 16, 4), 256, 0, stream>>>(q_buf, k_buf, vt_buf, slopes, attn_buf);
    // ---- Out-proj + residual -> x2 (bf16) ----
    conv_bf16<<<1024, 256, 0, stream>>>(Wo, wbuf, (2048 * 2048) / 8);
    conv_bf16<<<8, 256, 0, stream>>>(bo, bo_c, 2048 / 8);
    gemm_bt<1><<<(M / 128) * (2048 / 128), 256, 0, stream>>>(
        attn_buf, wbuf, bo_c, x, x2_buf, M, 2048, 2048);
    // ---- LN2(x2) -> h ----
    conv_bf16<<<8, 256, 0, stream>>>(ln2w, ln2w_c, 2048 / 8);
    conv_bf16<<<8, 256, 0, stream>>>(ln2b, ln2b_c, 2048 / 8);
    ln_kernel<0><<<M, 256, 0, stream>>>(x2_buf, ln2w_c, ln2b_c, h_buf);
    // ---- MLP up + GELU ----
    conv_bf16<<<2048, 256, 0, stream>>>(W1, wbuf, (8192 * 2048) / 8);
    conv_bf16<<<8, 256, 0, stream>>>(b1, b1_c, 8192 / 8);
    gemm_bt<2><<<(M / 128) * (8192 / 128), 256, 0, stream>>>(
        h_buf, wbuf, b1_c, nullptr, act_buf, M, 8192, 2048);
    // ---- MLP down + residual -> out (fp32) ----
    conv_bf16<<<2048, 256, 0, stream>>>(W2, wbuf, (2048 * 8192) / 8);
    conv_bf16<<<8, 256, 0, stream>>>(b2, b2_c, 2048 / 8);
    gemm_bt<3><<<(M / 128) * (2048 / 128), 256, 0, stream>>>(
        act_buf, wbuf, b2_c, x2_buf, outp, M, 2048, 8192);
}